// Round 2
// baseline (1691.008 us; speedup 1.0000x reference)
//
#include <hip/hip_runtime.h>
#include <cstdint>

typedef unsigned short ushort_t;
typedef __bf16 bf16x8 __attribute__((ext_vector_type(8)));
typedef float f32x4 __attribute__((ext_vector_type(4)));

// ---- constants for this problem ----
// B=128, T=25, E=512, H=1024, V=32000, ENC=400
// K (padded input dim) = 1024 everywhere.
// Gate layout is ROW-PERMUTED everywhere: permuted row p = 4*unit + gate,
// original row = (p&3)*1024 + (p>>2)  (gate order i,f,g,o).

__device__ __forceinline__ ushort_t f2bf(float f) {
    unsigned u = __float_as_uint(f);
    unsigned r = (u + 0x7fffu + ((u >> 16) & 1u)) >> 16;
    return (ushort_t)r;
}

// ---------------- conversion / setup kernels ----------------

// float -> bf16, 4 elements per thread, n multiple of 4
__global__ void cvt4(const float* __restrict__ S, ushort_t* __restrict__ D, int n) {
    int i = (blockIdx.x * 256 + threadIdx.x) * 4;
    if (i >= n) return;
    float4 v = *(const float4*)(S + i);
    ushort4 o;
    o.x = f2bf(v.x); o.y = f2bf(v.y); o.z = f2bf(v.z); o.w = f2bf(v.w);
    *(ushort4*)(D + i) = o;
}

// W_ih [4096,912] -> bf16 padded [4096,1024], rows permuted to 4u+g order
__global__ void cvt_wih(const float* __restrict__ W, ushort_t* __restrict__ D) {
    int idx = blockIdx.x * 256 + threadIdx.x;   // 4096*1024
    int p = idx >> 10, col = idx & 1023;
    int orig = (p & 3) * 1024 + (p >> 2);
    D[idx] = (col < 912) ? f2bf(W[orig * 912 + col]) : (ushort_t)0;
}

// W_hh [4096,1024] -> bf16, rows permuted to 4u+g order
__global__ void cvt_whh(const float* __restrict__ W, ushort_t* __restrict__ D) {
    int idx = blockIdx.x * 256 + threadIdx.x;   // 4096*1024
    int p = idx >> 10, col = idx & 1023;
    int orig = (p & 3) * 1024 + (p >> 2);
    D[idx] = f2bf(W[orig * 1024 + col]);
}

// combined permuted bias: bc[p] = b_ih[orig] + b_hh[orig]
__global__ void bias_prep(const float* __restrict__ bi, const float* __restrict__ bh,
                          float* __restrict__ bc) {
    int p = blockIdx.x * 256 + threadIdx.x;     // 4096
    int orig = (p & 3) * 1024 + (p >> 2);
    bc[p] = bi[orig] + bh[orig];
}

// X_all bf16 [3200,1024]: row r = t*128+b; cols 0..511 word emb, 512..911 features, rest 0
__global__ void build_xall(const float* __restrict__ features, const int* __restrict__ captions,
                           const float* __restrict__ embW, ushort_t* __restrict__ X) {
    int idx = blockIdx.x * 256 + threadIdx.x;   // 3200*1024
    int r = idx >> 10, col = idx & 1023;
    int t = r >> 7, b = r & 127;
    float v;
    if (col < 512) {
        int tok = (t == 0) ? 1 : captions[b * 25 + (t - 1)];
        v = embW[tok * 512 + col];
    } else if (col < 912) {
        v = features[b * 400 + (col - 512)];
    } else {
        v = 0.f;
    }
    X[idx] = f2bf(v);
}

// ---------------- bf16 GEMM, C = A * B^T (+epilogue) ----------------
// A: [M,K] bf16 row-major, B: [N,K] bf16 row-major, K multiple of 64 (=1024 here).
// Tile 128x128, BK=64, 256 threads = 4 waves, each wave 64x64 via 4x4 mfma 16x16x32.
// mode 2: out[(gm&127)*24*32000 + (gm>>7)*32000 + gn] = acc + bias[gn]
// mode 3: C[gm*ldc+gn] = acc + bias[gn]
// NOTE: round-1 XCD remap experiment REVERTED — it cut FETCH 807->301MB but
// slowed the kernel 410->467us (drain-latency-bound, not BW-bound; fewer
// independent HBM streams lengthened per-load latency).
__global__ __launch_bounds__(256)
void gemm_bt(const ushort_t* __restrict__ A, const ushort_t* __restrict__ B,
             float* __restrict__ C, const float* __restrict__ bias, int K, int mode) {
    const int ldc  = gridDim.x * 128;
    const int bm = blockIdx.y, bn = blockIdx.x;
    const int tid  = threadIdx.x;
    const int wave = tid >> 6, lane = tid & 63;

    __shared__ __align__(16) ushort_t As[128 * 64];
    __shared__ __align__(16) ushort_t Bs[128 * 64];

    const ushort_t* Ab = A + (size_t)bm * 128 * K;
    const ushort_t* Bb = B + (size_t)bn * 128 * K;

    f32x4 acc[4][4] = {};

    const int wm = (wave & 1) * 64;
    const int wn = (wave >> 1) * 64;

    for (int k0 = 0; k0 < K; k0 += 64) {
#pragma unroll
        for (int ro = 0; ro < 4; ++ro) {
            int L   = ro * 256 + tid;       // 0..1023 chunk index (16B chunks)
            int row = L >> 3;               // 0..127
            int cs  = (L & 7) ^ (row & 7);  // swizzled source chunk within row
            const ushort_t* ga = Ab + row * K + k0 + cs * 8;
            const ushort_t* gb = Bb + row * K + k0 + cs * 8;
            __builtin_amdgcn_global_load_lds(
                (const __attribute__((address_space(1))) void*)ga,
                (__attribute__((address_space(3))) void*)(As + L * 8), 16, 0, 0);
            __builtin_amdgcn_global_load_lds(
                (const __attribute__((address_space(1))) void*)gb,
                (__attribute__((address_space(3))) void*)(Bs + L * 8), 16, 0, 0);
        }
        __syncthreads();   // drains vmcnt(0) then barrier -> LDS ready

#pragma unroll
        for (int kk = 0; kk < 2; ++kk) {
            bf16x8 af[4], bfr[4];
#pragma unroll
            for (int mt = 0; mt < 4; ++mt) {
                int row = wm + mt * 16 + (lane & 15);
                int cc  = (kk * 4 + (lane >> 4)) ^ (row & 7);
                af[mt]  = *(const bf16x8*)(As + row * 64 + cc * 8);
            }
#pragma unroll
            for (int nt = 0; nt < 4; ++nt) {
                int row = wn + nt * 16 + (lane & 15);
                int cc  = (kk * 4 + (lane >> 4)) ^ (row & 7);
                bfr[nt] = *(const bf16x8*)(Bs + row * 64 + cc * 8);
            }
#pragma unroll
            for (int mt = 0; mt < 4; ++mt)
#pragma unroll
                for (int nt = 0; nt < 4; ++nt)
                    acc[mt][nt] = __builtin_amdgcn_mfma_f32_16x16x32_bf16(
                        af[mt], bfr[nt], acc[mt][nt], 0, 0, 0);
        }
        __syncthreads();   // protect LDS before next stage overwrites
    }

    // epilogue: C/D layout col=lane&15, row=(lane>>4)*4+reg (m89/m91-verified)
    const int r0 = (lane >> 4) * 4;
    const int cn = lane & 15;
#pragma unroll
    for (int mt = 0; mt < 4; ++mt) {
#pragma unroll
        for (int nt = 0; nt < 4; ++nt) {
#pragma unroll
            for (int r = 0; r < 4; ++r) {
                int m  = wm + mt * 16 + r0 + r;
                int n  = wn + nt * 16 + cn;
                int gm = bm * 128 + m;
                int gn = bn * 128 + n;
                float v = acc[mt][nt][r];
                if (mode == 3) {
                    C[(size_t)gm * ldc + gn] = v + bias[gn];
                } else {
                    // gm = (t-1)*128 + b -> out[b, t-1, gn]
                    C[(size_t)(gm & 127) * (24 * 32000) + (size_t)(gm >> 7) * 32000 + gn]
                        = v + bias[gn];
                }
            }
        }
    }
}

// ---------------- persistent fused LSTM: all 25 steps in one launch ----------------
// 256 blocks (1/CU). Block bn owns permuted gate-cols [bn*16, bn*16+16) = natural
// units bn*4..bn*4+3 (all 4 gates). Whh fragments persist in REGISTERS (32 x bf16x8).
// h read directly from global (L2-hot) in MFMA fragment pattern; c lives in LDS for
// all 25 steps. Steps separated by a device-scope monotonic grid barrier
// (threadfence = L2 writeback/invalidate for cross-XCD h visibility).
#define NBLK 256
__global__ __launch_bounds__(256, 1)
void lstm_persistent(const ushort_t* __restrict__ Whh,   // permuted [4096,1024] bf16
                     const float* __restrict__ gin_all,  // [25][128][4096] f32 (bias baked)
                     ushort_t* __restrict__ hbuf0,       // [128,1024] bf16 (h at t=0)
                     ushort_t* __restrict__ Hall,        // [24][128][1024] bf16
                     int* cnt) {
    const int bn   = blockIdx.x;          // 0..255
    const int tid  = threadIdx.x;
    const int wave = tid >> 6, lane = tid & 63;

    __shared__ __align__(16) float gt[128 * 20];   // gate tile [128][16], pad 20
    __shared__ float c_s[128 * 4];                 // cell state, persistent

    // persistent B fragments: lane holds col bn*16+(lane&15), k-chunk (lane>>4)*8
    const int colp = bn * 16 + (lane & 15);
    const int kc   = (lane >> 4) * 8;
    bf16x8 barr[32];
#pragma unroll
    for (int kk = 0; kk < 32; ++kk)
        barr[kk] = *(const bf16x8*)(Whh + (size_t)colp * 1024 + kk * 32 + kc);

    for (int i = tid; i < 512; i += 256) c_s[i] = 0.f;
    __syncthreads();

    const int mrow0 = wave * 32;          // wave owns M rows [mrow0, mrow0+32)
    const int r0 = (lane >> 4) * 4;
    const int cn = lane & 15;
    const int ul = tid & 3;               // local unit 0..3
    const int b0 = tid >> 2;              // batch row 0..63 (and +64)

    for (int t = 0; t < 25; ++t) {
        f32x4 acc0 = {}, acc1 = {};
        if (t > 0) {
            const ushort_t* hin = (t == 1) ? hbuf0 : Hall + (size_t)(t - 2) * 131072;
            const ushort_t* a0 = hin + (size_t)(mrow0 + (lane & 15)) * 1024 + kc;
            const ushort_t* a1 = a0 + 16 * 1024;
#pragma unroll
            for (int kk = 0; kk < 32; ++kk) {
                bf16x8 af0 = *(const bf16x8*)(a0 + kk * 32);
                bf16x8 af1 = *(const bf16x8*)(a1 + kk * 32);
                acc0 = __builtin_amdgcn_mfma_f32_16x16x32_bf16(af0, barr[kk], acc0, 0, 0, 0);
                acc1 = __builtin_amdgcn_mfma_f32_16x16x32_bf16(af1, barr[kk], acc1, 0, 0, 0);
            }
        }
        // gates tile -> LDS (gin already carries both biases; t=0: gates = gin)
        const float* gin = gin_all + (size_t)t * 524288;
#pragma unroll
        for (int r = 0; r < 4; ++r) {
            int m0 = mrow0 + r0 + r;
            int m1 = m0 + 16;
            gt[m0 * 20 + cn] = acc0[r] + gin[(size_t)m0 * 4096 + bn * 16 + cn];
            gt[m1 * 20 + cn] = acc1[r] + gin[(size_t)m1 * 4096 + bn * 16 + cn];
        }
        __syncthreads();

        // cell: thread handles (b0, ul) and (b0+64, ul)
        ushort_t* hout = (t == 0) ? hbuf0 : Hall + (size_t)(t - 1) * 131072;
#pragma unroll
        for (int hh = 0; hh < 2; ++hh) {
            int b = b0 + hh * 64;
            float4 g4 = *(const float4*)(gt + b * 20 + ul * 4);   // i,f,g,o
            float si = 1.f / (1.f + expf(-g4.x));
            float sf = 1.f / (1.f + expf(-g4.y));
            float so = 1.f / (1.f + expf(-g4.w));
            float cnew = sf * c_s[b * 4 + ul] + si * tanhf(g4.z);
            c_s[b * 4 + ul] = cnew;
            hout[(size_t)b * 1024 + bn * 4 + ul] = f2bf(so * tanhf(cnew));
        }
        __syncthreads();   // h stores done (vmcnt drained) + gt safe to reuse

        if (t < 24) {      // grid barrier: h(t) visible before anyone reads it at t+1
            if (tid == 0) {
                __threadfence();   // writeback this XCD's L2 (h -> device-visible)
                __hip_atomic_fetch_add(cnt, 1, __ATOMIC_RELEASE, __HIP_MEMORY_SCOPE_AGENT);
                const int tgt = NBLK * (t + 1);
                while (__hip_atomic_load(cnt, __ATOMIC_ACQUIRE, __HIP_MEMORY_SCOPE_AGENT) < tgt)
                    __builtin_amdgcn_s_sleep(2);
                __threadfence();   // invalidate stale lines before reading new h
            }
            __syncthreads();
        }
    }
}

// ---------------- launch ----------------

extern "C" void kernel_launch(void* const* d_in, const int* in_sizes, int n_in,
                              void* d_out, int out_size, void* d_ws, size_t ws_size,
                              hipStream_t stream) {
    const float* features = (const float*)d_in[0];
    const int*   captions = (const int*)d_in[1];
    const float* emb_W    = (const float*)d_in[2];
    const float* W_ih     = (const float*)d_in[3];
    const float* W_hh     = (const float*)d_in[4];
    const float* b_ih     = (const float*)d_in[5];
    const float* b_hh     = (const float*)d_in[6];
    // d_in[7..12]: attention weights — provably dead code (softmax over 1 pixel)
    const float* fcn_W    = (const float*)d_in[13];
    const float* fcn_b    = (const float*)d_in[14];
    float* out = (float*)d_out;

    char* p = (char*)d_ws;
    auto alloc = [&](size_t bytes) { void* r = p; p += bytes; return r; };
    ushort_t* Xall     = (ushort_t*)alloc((size_t)3200 * 1024 * 2);   // 6.55 MB
    ushort_t* Wihb     = (ushort_t*)alloc((size_t)4096 * 1024 * 2);   // 8.39 MB (permuted)
    ushort_t* Whhb     = (ushort_t*)alloc((size_t)4096 * 1024 * 2);   // 8.39 MB (permuted)
    ushort_t* Fcnb     = (ushort_t*)alloc((size_t)32000 * 1024 * 2);  // 65.5 MB
    float*    gates_in = (float*)alloc((size_t)3200 * 4096 * 4);      // 52.4 MB (permuted, bias baked)
    float*    bc       = (float*)alloc((size_t)4096 * 4);             // 16 KB
    ushort_t* Hall     = (ushort_t*)alloc((size_t)3072 * 1024 * 2);   // 6.29 MB (h_2..h_25)
    ushort_t* hbuf0    = (ushort_t*)alloc((size_t)128 * 1024 * 2);
    int*      cnt      = (int*)alloc(256);
    (void)ws_size; (void)n_in; (void)in_sizes; (void)out_size;

    // ws is poisoned before every timed launch -> zero the barrier counter
    hipMemsetAsync(cnt, 0, 256, stream);

    // weight conversions (gate-permuted) + X_all + combined bias
    build_xall<<<(3200 * 1024) / 256, 256, 0, stream>>>(features, captions, emb_W, Xall);
    cvt_wih<<<(4096 * 1024) / 256, 256, 0, stream>>>(W_ih, Wihb);
    cvt_whh<<<(4096 * 1024) / 256, 256, 0, stream>>>(W_hh, Whhb);
    cvt4<<<(32000 * 1024) / 1024, 256, 0, stream>>>(fcn_W, Fcnb, 32000 * 1024);
    bias_prep<<<16, 256, 0, stream>>>(b_ih, b_hh, bc);

    // gates_in[3200,4096] = X_all @ W_ih_pad^T + (b_ih+b_hh)   (permuted col order)
    gemm_bt<<<dim3(32, 25), 256, 0, stream>>>(Xall, Wihb, gates_in, bc, 1024, 3);

    // all 25 recurrent steps in one persistent launch
    lstm_persistent<<<NBLK, 256, 0, stream>>>(Whhb, gates_in, hbuf0, Hall, cnt);

    // out[b, t-1, :] = Hall @ fcn_W^T + fcn_b
    gemm_bt<<<dim3(250, 24), 256, 0, stream>>>(Hall, Fcnb, out, fcn_b, 1024, 2);
}